// Round 6
// baseline (339.882 us; speedup 1.0000x reference)
//
#include <hip/hip_runtime.h>
#include <hip/hip_fp16.h>

#define NN 50000
#define EE 800000
#define ET (EE + NN)      // edges + self loops = 850000
#define IND 128
#define F1 256            // HEADS*HID
#define H1 8
#define D1 32
#define F2 64
#define NEG 0.2f
#define EPSV 1e-16f

typedef _Float16 half8_t __attribute__((ext_vector_type(8)));
typedef _Float16 half4_t __attribute__((ext_vector_type(4)));
typedef float floatx4 __attribute__((ext_vector_type(4)));

// ---------------- CSR build ----------------
__global__ void k_hist(const int* __restrict__ ei, int* __restrict__ deg) {
  int e = blockIdx.x * blockDim.x + threadIdx.x;
  if (e >= ET) return;
  int d = (e < EE) ? ei[EE + e] : (e - EE);
  atomicAdd(&deg[d], 1);
}

__global__ void k_scan1(const int* __restrict__ deg, int* __restrict__ incl,
                        int* __restrict__ blks) {
  __shared__ int sm[256];
  int t = threadIdx.x;
  int i = blockIdx.x * 256 + t;
  int v = (i < NN) ? deg[i] : 0;
  sm[t] = v;
  __syncthreads();
  for (int off = 1; off < 256; off <<= 1) {
    int add = (t >= off) ? sm[t - off] : 0;
    __syncthreads();
    sm[t] += add;
    __syncthreads();
  }
  if (i < NN) incl[i] = sm[t];
  if (t == 255) blks[blockIdx.x] = sm[t];
}

__global__ void k_scan2(int* __restrict__ blks, int nb) {
  __shared__ int sm[256];
  int t = threadIdx.x;
  sm[t] = (t < nb) ? blks[t] : 0;
  __syncthreads();
  for (int off = 1; off < 256; off <<= 1) {
    int add = (t >= off) ? sm[t - off] : 0;
    __syncthreads();
    sm[t] += add;
    __syncthreads();
  }
  if (t < nb) blks[t] = sm[t];
}

__global__ void k_scan3(const int* __restrict__ deg, const int* __restrict__ blks,
                        int* __restrict__ rowp, int* __restrict__ cursor) {
  int b = blockIdx.x;
  int i = b * 256 + threadIdx.x;
  if (i == 0) rowp[NN] = ET;
  if (i >= NN) return;
  int base = (b > 0) ? blks[b - 1] : 0;
  int excl = rowp[i] - deg[i] + base;
  rowp[i] = excl;
  cursor[i] = excl;
}

__global__ void k_scatter(const int* __restrict__ ei, int* __restrict__ cursor,
                          int* __restrict__ csr) {
  int e = blockIdx.x * blockDim.x + threadIdx.x;
  if (e >= ET) return;
  int s, d;
  if (e < EE) { s = ei[e]; d = ei[EE + e]; }
  else        { s = e - EE; d = s; }
  int pos = atomicAdd(&cursor[d], 1);
  csr[pos] = s;
}

// ---------------- fp32 -> fp16 convert for W1 | W2 ----------------
#define W1N4 (256 * 128 / 4)
#define W2N4 (64 * 256 / 4)
__global__ void k_cvtW(const float* __restrict__ w1, const float* __restrict__ w2,
                       __half* __restrict__ w1h, __half* __restrict__ w2h) {
  int i = blockIdx.x * blockDim.x + threadIdx.x;
  const float* in;
  __half* o;
  if (i < W1N4) { in = w1; o = w1h; }
  else if (i < W1N4 + W2N4) { in = w2; o = w2h; i -= W1N4; }
  else return;
  float4 v = *(const float4*)(in + (size_t)i * 4);
  __half2 p0 = __floats2half2_rn(v.x, v.y);
  __half2 p1 = __floats2half2_rn(v.z, v.w);
  float2 st;
  *(__half2*)&st.x = p0;
  *(__half2*)&st.y = p1;
  *(float2*)(o + (size_t)i * 4) = st;
}

// ---------------- MFMA GEMM, sliced fp16 output ----------------
// C = A[M,K] * B[NC,K]^T. Output layout [NC/32][M][32] fp16 (head-sliced).
// A dtype templated (fp32 converted in-register, or fp16 direct).
template<int NCT, int K, typename AT>
__global__ __launch_bounds__(256) void k_gemm_mf(const AT* __restrict__ A,
    const __half* __restrict__ Bh, __half* __restrict__ Ch, int M) {
  __shared__ __half Bs[NCT][K + 8];
  int tid = threadIdx.x;
  const float4* src = (const float4*)(Bh + (size_t)blockIdx.y * NCT * K);
  for (int i = tid; i < NCT * K / 8; i += 256) {
    int row = i / (K / 8), kc = i % (K / 8);
    *(float4*)&Bs[row][kc * 8] = src[i];
  }
  __syncthreads();
  int wv = tid >> 6, lane = tid & 63;
  int m0 = blockIdx.x * 64 + wv * 16;
  int ar = lane & 15, ag = lane >> 4;
  int mrow = m0 + ar;
  if (mrow >= M) mrow = M - 1;
  const AT* Arow = A + (size_t)mrow * K + ag * 8;
  floatx4 acc[NCT / 16];
#pragma unroll
  for (int t = 0; t < NCT / 16; ++t) acc[t] = (floatx4){0.f, 0.f, 0.f, 0.f};
#pragma unroll
  for (int k0 = 0; k0 < K; k0 += 32) {
    half8_t af;
    if constexpr (sizeof(AT) == 4) {
      float4 a0 = *(const float4*)(Arow + k0);
      float4 a1 = *(const float4*)(Arow + k0 + 4);
      af[0] = (_Float16)a0.x; af[1] = (_Float16)a0.y;
      af[2] = (_Float16)a0.z; af[3] = (_Float16)a0.w;
      af[4] = (_Float16)a1.x; af[5] = (_Float16)a1.y;
      af[6] = (_Float16)a1.z; af[7] = (_Float16)a1.w;
    } else {
      af = *(const half8_t*)(Arow + k0);
    }
#pragma unroll
    for (int t = 0; t < NCT / 16; ++t) {
      half8_t bf = *(const half8_t*)&Bs[t * 16 + ar][k0 + ag * 8];
      acc[t] = __builtin_amdgcn_mfma_f32_16x16x32_f16(af, bf, acc[t], 0, 0, 0);
    }
  }
#pragma unroll
  for (int t = 0; t < NCT / 16; ++t) {
    int col = blockIdx.y * NCT + t * 16 + ar;
#pragma unroll
    for (int r = 0; r < 4; ++r) {
      int m = m0 + ag * 4 + r;
      if (m < M)
        Ch[((size_t)(col >> 5) * M + m) * 32 + (col & 31)] = __float2half(acc[t][r]);
    }
  }
}

// ---------------- attention logits from sliced feat ----------------
// feat [F/32][N][32] fp16. Lane handles one 16B chunk (8 dims).
template<int H, int D>
__global__ void k_att2s(const __half* __restrict__ feat, const float* __restrict__ atts,
                        const float* __restrict__ attd, float* __restrict__ as_,
                        float* __restrict__ ad_) {
  const int F = H * D;
  const int CPR = F / 8;          // chunks per row
  const int NPW = 64 / CPR;       // nodes per wave
  const int CPH = D / 8;          // chunks per head
  int lane = threadIdx.x & 63;
  int wvi = threadIdx.x >> 6;
  int n = blockIdx.x * (4 * NPW) + wvi * NPW + lane / CPR;
  if (n >= NN) return;
  int c = lane % CPR;
  int head = c / CPH;
  int within = c % CPH;
  // sliced addr: slice = c>>2, elem = (c&3)*8
  half8_t f = *(const half8_t*)(feat + ((size_t)(c >> 2) * NN + n) * 32 + (c & 3) * 8);
  float s_ = 0.f, d_ = 0.f;
#pragma unroll
  for (int j = 0; j < 8; ++j) {
    float fv = (float)f[j];
    s_ += fv * atts[head * D + within * 8 + j];
    d_ += fv * attd[head * D + within * 8 + j];
  }
#pragma unroll
  for (int m = 1; m < CPH; m <<= 1) {
    s_ += __shfl_xor(s_, m);
    d_ += __shfl_xor(d_, m);
  }
  if (within == 0) {
    as_[n * H + head] = s_;
    ad_[n * H + head] = d_;
  }
}

// ---------------- pass A: per-edge weights, layer 1 (8 heads) -------------
// wave/dest; lane = (slot 0..7, head 0..7). w1t[8][ET] fp16, inv1t[8][N].
__global__ __launch_bounds__(256) void k_wgt8(const int* __restrict__ rowp,
    const int* __restrict__ csr, const float* __restrict__ as_,
    const float* __restrict__ ad_, __half* __restrict__ wt,
    float* __restrict__ invt) {
  int wid = threadIdx.x >> 6;
  int lane = threadIdx.x & 63;
  int d = blockIdx.x * 4 + wid;
  if (d >= NN) return;
  int sw = lane >> 3, hw = lane & 7;
  float adw = ad_[d * 8 + hw];
  float ws = 0.f;
  int p0 = rowp[d], p1 = rowp[d + 1];
  for (int p = p0; p < p1; p += 8) {
    int pe = p + sw;
    bool v = pe < p1;
    int pc = v ? pe : p1 - 1;
    int sW = csr[pc];
    float t = as_[sW * 8 + hw] + adw;
    t = (t > 0.f) ? t : NEG * t;
    float w = v ? __expf(t) : 0.f;
    ws += w;
    if (v) wt[(size_t)hw * ET + pe] = __float2half(w);
  }
  ws += __shfl_xor(ws, 8);
  ws += __shfl_xor(ws, 16);
  ws += __shfl_xor(ws, 32);
  if (sw == 0) invt[(size_t)hw * NN + d] = 1.f / (ws + EPSV);
}

// ---------------- pass A: per-edge weights, layer 2 (1 head) --------------
__global__ __launch_bounds__(256) void k_wgt1(const int* __restrict__ rowp,
    const int* __restrict__ csr, const float* __restrict__ as_,
    const float* __restrict__ ad_, __half* __restrict__ wt,
    float* __restrict__ inv2) {
  int wid = threadIdx.x >> 6;
  int lane = threadIdx.x & 63;
  int d = blockIdx.x * 4 + wid;
  if (d >= NN) return;
  float adv = ad_[d];
  float ws = 0.f;
  int p0 = rowp[d], p1 = rowp[d + 1];
  for (int p = p0 + lane; p < p1; p += 64) {
    int s = csr[p];
    float t = as_[s] + adv;
    t = (t > 0.f) ? t : NEG * t;
    float w = __expf(t);
    ws += w;
    wt[p] = __float2half(w);
  }
  ws += __shfl_xor(ws, 1);  ws += __shfl_xor(ws, 2);
  ws += __shfl_xor(ws, 4);  ws += __shfl_xor(ws, 8);
  ws += __shfl_xor(ws, 16); ws += __shfl_xor(ws, 32);
  if (lane == 0) inv2[d] = 1.f / (ws + EPSV);
}

// ---------------- pass B: sliced weighted gather, XCD-pinned --------------
// feat [NSLICE][N][32] fp16; slice = blockIdx.x % NSLICE pins each slice's
// 3.2MB to one XCD's L2. Wave/dest: 8 edges/iter x 8 lanes x 8B. Weights are
// precomputed (pass A) -> no exp/bpermute here.
template<int NSLICE, int WS, int IS, bool RELU, typename OT, int OF>
__global__ __launch_bounds__(256) void k_aggs(const int* __restrict__ rowp,
    const int* __restrict__ csr, const __half* __restrict__ wt,
    const float* __restrict__ invt, const __half* __restrict__ feat,
    const float* __restrict__ bias, OT* __restrict__ out) {
  int slice = blockIdx.x % NSLICE;
  int chunk = blockIdx.x / NSLICE;
  int wid = threadIdx.x >> 6;
  int lane = threadIdx.x & 63;
  int d = chunk * 4 + wid;
  if (d >= NN) return;
  const int b = lane >> 3;        // edge slot 0..7
  const int q = lane & 7;         // 8B chunk (4 dims)
  const __half* fb = feat + (size_t)slice * NN * 32 + q * 4;
  const __half* wb = wt + (size_t)slice * WS;
  float a0 = 0.f, a1 = 0.f, a2 = 0.f, a3 = 0.f;
  int p0 = rowp[d], p1 = rowp[d + 1];
  int nfull = (p1 - p0) >> 3;
  int p = p0;
#pragma unroll 2
  for (int it = 0; it < nfull; ++it, p += 8) {
    int se = csr[p + b];
    float wv = __half2float(wb[p + b]);
    half4_t f = *(const half4_t*)(fb + (size_t)se * 32);
    a0 = fmaf(wv, (float)f[0], a0);
    a1 = fmaf(wv, (float)f[1], a1);
    a2 = fmaf(wv, (float)f[2], a2);
    a3 = fmaf(wv, (float)f[3], a3);
  }
  if (p < p1) {
    int pe = p + b;
    bool v = pe < p1;
    int pc = v ? pe : p1 - 1;
    int se = csr[pc];
    float wv = v ? __half2float(wb[pc]) : 0.f;
    half4_t f = *(const half4_t*)(fb + (size_t)se * 32);
    a0 = fmaf(wv, (float)f[0], a0);
    a1 = fmaf(wv, (float)f[1], a1);
    a2 = fmaf(wv, (float)f[2], a2);
    a3 = fmaf(wv, (float)f[3], a3);
  }
  a0 += __shfl_xor(a0, 8); a0 += __shfl_xor(a0, 16); a0 += __shfl_xor(a0, 32);
  a1 += __shfl_xor(a1, 8); a1 += __shfl_xor(a1, 16); a1 += __shfl_xor(a1, 32);
  a2 += __shfl_xor(a2, 8); a2 += __shfl_xor(a2, 16); a2 += __shfl_xor(a2, 32);
  a3 += __shfl_xor(a3, 8); a3 += __shfl_xor(a3, 16); a3 += __shfl_xor(a3, 32);
  if (b == 0) {
    float inv = invt[(size_t)slice * IS + d];
    int d0 = slice * 32 + q * 4;
    float o0 = a0 * inv + bias[d0 + 0];
    float o1 = a1 * inv + bias[d0 + 1];
    float o2 = a2 * inv + bias[d0 + 2];
    float o3 = a3 * inv + bias[d0 + 3];
    if (RELU) {
      o0 = fmaxf(o0, 0.f); o1 = fmaxf(o1, 0.f);
      o2 = fmaxf(o2, 0.f); o3 = fmaxf(o3, 0.f);
    }
    if constexpr (sizeof(OT) == 2) {
      __half2 pk[2];
      pk[0] = __floats2half2_rn(o0, o1);
      pk[1] = __floats2half2_rn(o2, o3);
      *(float2*)((__half*)out + (size_t)d * OF + d0) = *(float2*)pk;
    } else {
      float4 o = make_float4(o0, o1, o2, o3);
      *(float4*)((float*)out + (size_t)d * OF + d0) = o;
    }
  }
}

extern "C" void kernel_launch(void* const* d_in, const int* in_sizes, int n_in,
                              void* d_out, int out_size, void* d_ws, size_t ws_size,
                              hipStream_t stream) {
  const float* x    = (const float*)d_in[0];
  const int*   ei   = (const int*)d_in[1];
  const float* W1   = (const float*)d_in[2];
  const float* as1w = (const float*)d_in[3];
  const float* ad1w = (const float*)d_in[4];
  const float* b1   = (const float*)d_in[5];
  const float* W2   = (const float*)d_in[6];
  const float* as2w = (const float*)d_in[7];
  const float* ad2w = (const float*)d_in[8];
  const float* b2   = (const float*)d_in[9];
  float* out = (float*)d_out;

  char* W = (char*)d_ws;
  __half* feat1 = (__half*)W; W += (size_t)8 * NN * 32 * 2;  // GEMM1 out, sliced
  __half* h2h   = (__half*)W; W += (size_t)NN * 256 * 2;     // agg1 out / GEMM2 A
  __half* feat2 = (__half*)W; W += (size_t)2 * NN * 32 * 2;  // GEMM2 out, sliced
  __half* W1h   = (__half*)W; W += 256 * 128 * 2;
  __half* W2h   = (__half*)W; W += 64 * 256 * 2;
  __half* w1t   = (__half*)W; W += (size_t)8 * ET * 2;       // [8][ET]
  __half* w2t   = (__half*)W; W += (size_t)ET * 2;           // [ET]
  float* as1   = (float*)W; W += (size_t)NN * 8 * 4;         // node-major [N][8]
  float* ad1   = (float*)W; W += (size_t)NN * 8 * 4;
  float* as2   = (float*)W; W += (size_t)NN * 4;
  float* ad2   = (float*)W; W += (size_t)NN * 4;
  float* inv1t = (float*)W; W += (size_t)8 * NN * 4;         // [8][N]
  float* inv2  = (float*)W; W += (size_t)NN * 4;
  int* deg    = (int*)W;  W += (size_t)NN * 4;
  int* rowp   = (int*)W;  W += (size_t)(NN + 1) * 4;
  int* cursor = (int*)W;  W += (size_t)NN * 4;
  int* blks   = (int*)W;  W += 256 * 4;
  int* csr    = (int*)W;  W += (size_t)ET * 4;

  hipMemsetAsync(deg, 0, NN * sizeof(int), stream);
  int nbE = (ET + 255) / 256;
  int nbN = (NN + 255) / 256;               // 196
  k_hist<<<nbE, 256, 0, stream>>>(ei, deg);
  k_scan1<<<nbN, 256, 0, stream>>>(deg, rowp, blks);
  k_scan2<<<1, 256, 0, stream>>>(blks, nbN);
  k_scan3<<<nbN, 256, 0, stream>>>(deg, blks, rowp, cursor);
  k_scatter<<<nbE, 256, 0, stream>>>(ei, cursor, csr);

  k_cvtW<<<(W1N4 + W2N4 + 255) / 256, 256, 0, stream>>>(W1, W2, W1h, W2h);

  int mg = (NN + 63) / 64;                  // 782
  int dg = (NN + 3) / 4;                    // 12500

  // layer 1
  k_gemm_mf<128, 128, float><<<dim3(mg, 2), 256, 0, stream>>>(x, W1h, feat1, NN);
  k_att2s<H1, D1><<<(NN + 7) / 8, 256, 0, stream>>>(feat1, as1w, ad1w, as1, ad1);
  k_wgt8<<<dg, 256, 0, stream>>>(rowp, csr, as1, ad1, w1t, inv1t);
  k_aggs<8, ET, NN, true, __half, 256><<<8 * dg, 256, 0, stream>>>(
      rowp, csr, w1t, inv1t, feat1, b1, h2h);

  // layer 2
  k_gemm_mf<64, 256, __half><<<dim3(mg, 1), 256, 0, stream>>>(h2h, W2h, feat2, NN);
  k_att2s<1, F2><<<(NN + 31) / 32, 256, 0, stream>>>(feat2, as2w, ad2w, as2, ad2);
  k_wgt1<<<dg, 256, 0, stream>>>(rowp, csr, as2, ad2, w2t, inv2);
  k_aggs<2, 0, 0, false, float, 64><<<2 * dg, 256, 0, stream>>>(
      rowp, csr, w2t, inv2, feat2, b2, out);
}

// Round 7
// 272.158 us; speedup vs baseline: 1.2488x; 1.2488x over previous
//
#include <hip/hip_runtime.h>
#include <hip/hip_fp16.h>

#define NN 50000
#define EE 800000
#define ET (EE + NN)      // edges + self loops = 850000 (multiple of 8)
#define IND 128
#define F1 256            // HEADS*HID
#define H1 8
#define D1 32
#define F2 64
#define NEG 0.2f
#define EPSV 1e-16f

typedef _Float16 half8_t __attribute__((ext_vector_type(8)));
typedef _Float16 half4_t __attribute__((ext_vector_type(4)));
typedef _Float16 half2_t __attribute__((ext_vector_type(2)));
typedef float floatx4 __attribute__((ext_vector_type(4)));

// ---------------- CSR build ----------------
__global__ void k_hist(const int* __restrict__ ei, int* __restrict__ deg) {
  int e = blockIdx.x * blockDim.x + threadIdx.x;
  if (e >= ET) return;
  int d = (e < EE) ? ei[EE + e] : (e - EE);
  atomicAdd(&deg[d], 1);
}

__global__ void k_scan1(const int* __restrict__ deg, int* __restrict__ incl,
                        int* __restrict__ blks) {
  __shared__ int sm[256];
  int t = threadIdx.x;
  int i = blockIdx.x * 256 + t;
  int v = (i < NN) ? deg[i] : 0;
  sm[t] = v;
  __syncthreads();
  for (int off = 1; off < 256; off <<= 1) {
    int add = (t >= off) ? sm[t - off] : 0;
    __syncthreads();
    sm[t] += add;
    __syncthreads();
  }
  if (i < NN) incl[i] = sm[t];
  if (t == 255) blks[blockIdx.x] = sm[t];
}

__global__ void k_scan2(int* __restrict__ blks, int nb) {
  __shared__ int sm[256];
  int t = threadIdx.x;
  sm[t] = (t < nb) ? blks[t] : 0;
  __syncthreads();
  for (int off = 1; off < 256; off <<= 1) {
    int add = (t >= off) ? sm[t - off] : 0;
    __syncthreads();
    sm[t] += add;
    __syncthreads();
  }
  if (t < nb) blks[t] = sm[t];
}

__global__ void k_scan3(const int* __restrict__ deg, const int* __restrict__ blks,
                        int* __restrict__ rowp, int* __restrict__ cursor) {
  int b = blockIdx.x;
  int i = b * 256 + threadIdx.x;
  if (i == 0) rowp[NN] = ET;
  if (i >= NN) return;
  int base = (b > 0) ? blks[b - 1] : 0;
  int excl = rowp[i] - deg[i] + base;
  rowp[i] = excl;
  cursor[i] = excl;
}

__global__ void k_scatter(const int* __restrict__ ei, int* __restrict__ cursor,
                          int* __restrict__ csr) {
  int e = blockIdx.x * blockDim.x + threadIdx.x;
  if (e >= ET) return;
  int s, d;
  if (e < EE) { s = ei[e]; d = ei[EE + e]; }
  else        { s = e - EE; d = s; }
  int pos = atomicAdd(&cursor[d], 1);
  csr[pos] = s;
}

// ---------------- fp32 -> fp16 convert for W1 | W2 ----------------
#define W1N4 (256 * 128 / 4)
#define W2N4 (64 * 256 / 4)
__global__ void k_cvtW(const float* __restrict__ w1, const float* __restrict__ w2,
                       __half* __restrict__ w1h, __half* __restrict__ w2h) {
  int i = blockIdx.x * blockDim.x + threadIdx.x;
  const float* in;
  __half* o;
  if (i < W1N4) { in = w1; o = w1h; }
  else if (i < W1N4 + W2N4) { in = w2; o = w2h; i -= W1N4; }
  else return;
  float4 v = *(const float4*)(in + (size_t)i * 4);
  __half2 p0 = __floats2half2_rn(v.x, v.y);
  __half2 p1 = __floats2half2_rn(v.z, v.w);
  float2 st;
  *(__half2*)&st.x = p0;
  *(__half2*)&st.y = p1;
  *(float2*)(o + (size_t)i * 4) = st;
}

// ---------------- MFMA GEMM: Ch[M,NCF] = A[M,K] * B[NC,K]^T ----------------
// Row-major fp16 output. A dtype templated (fp32 converted in-register).
template<int NCT, int K, int NCF, typename AT>
__global__ __launch_bounds__(256) void k_gemm_mf(const AT* __restrict__ A,
    const __half* __restrict__ Bh, __half* __restrict__ Ch, int M) {
  __shared__ __half Bs[NCT][K + 8];
  int tid = threadIdx.x;
  const float4* src = (const float4*)(Bh + (size_t)blockIdx.y * NCT * K);
  for (int i = tid; i < NCT * K / 8; i += 256) {
    int row = i / (K / 8), kc = i % (K / 8);
    *(float4*)&Bs[row][kc * 8] = src[i];
  }
  __syncthreads();
  int wv = tid >> 6, lane = tid & 63;
  int m0 = blockIdx.x * 64 + wv * 16;
  int ar = lane & 15, ag = lane >> 4;
  int mrow = m0 + ar;
  if (mrow >= M) mrow = M - 1;
  const AT* Arow = A + (size_t)mrow * K + ag * 8;
  floatx4 acc[NCT / 16];
#pragma unroll
  for (int t = 0; t < NCT / 16; ++t) acc[t] = (floatx4){0.f, 0.f, 0.f, 0.f};
#pragma unroll
  for (int k0 = 0; k0 < K; k0 += 32) {
    half8_t af;
    if constexpr (sizeof(AT) == 4) {
      float4 a0 = *(const float4*)(Arow + k0);
      float4 a1 = *(const float4*)(Arow + k0 + 4);
      af[0] = (_Float16)a0.x; af[1] = (_Float16)a0.y;
      af[2] = (_Float16)a0.z; af[3] = (_Float16)a0.w;
      af[4] = (_Float16)a1.x; af[5] = (_Float16)a1.y;
      af[6] = (_Float16)a1.z; af[7] = (_Float16)a1.w;
    } else {
      af = *(const half8_t*)(Arow + k0);
    }
#pragma unroll
    for (int t = 0; t < NCT / 16; ++t) {
      half8_t bf = *(const half8_t*)&Bs[t * 16 + ar][k0 + ag * 8];
      acc[t] = __builtin_amdgcn_mfma_f32_16x16x32_f16(af, bf, acc[t], 0, 0, 0);
    }
  }
#pragma unroll
  for (int t = 0; t < NCT / 16; ++t) {
    int col = blockIdx.y * NCT + t * 16 + ar;
#pragma unroll
    for (int r = 0; r < 4; ++r) {
      int m = m0 + ag * 4 + r;
      if (m < M) Ch[(size_t)m * NCF + col] = __float2half(acc[t][r]);
    }
  }
}

// ---------------- per-node attention logits, coalesced (row-major feat) ----
template<int H, int D>
__global__ void k_att2(const __half* __restrict__ h, const float* __restrict__ atts,
                       const float* __restrict__ attd, float* __restrict__ as_,
                       float* __restrict__ ad_) {
  const int F = H * D;
  const int CPR = F / 8;          // chunks per row
  const int NPW = 64 / CPR;       // nodes per wave
  const int CPH = D / 8;          // chunks per head
  int lane = threadIdx.x & 63;
  int wv = threadIdx.x >> 6;
  int n = blockIdx.x * (4 * NPW) + wv * NPW + lane / CPR;
  if (n >= NN) return;
  int c = lane % CPR;
  int head = c / CPH;
  int within = c % CPH;
  half8_t f = *(const half8_t*)(h + (size_t)n * F + c * 8);
  float s_ = 0.f, d_ = 0.f;
#pragma unroll
  for (int j = 0; j < 8; ++j) {
    float fv = (float)f[j];
    s_ += fv * atts[head * D + within * 8 + j];
    d_ += fv * attd[head * D + within * 8 + j];
  }
#pragma unroll
  for (int m = 1; m < CPH; m <<= 1) {
    s_ += __shfl_xor(s_, m);
    d_ += __shfl_xor(d_, m);
  }
  if (within == 0) {
    as_[n * H + head] = s_;
    ad_[n * H + head] = d_;
  }
}

// ---------------- pass A: per-edge weights, layer 1 (8 heads) -------------
// wave/dest; lane = (slot 0..7, head 0..7). wt[8][ET] fp16; inv [N][8] fp32.
__global__ __launch_bounds__(256) void k_wgt8(const int* __restrict__ rowp,
    const int* __restrict__ csr, const float* __restrict__ as_,
    const float* __restrict__ ad_, __half* __restrict__ wt,
    float* __restrict__ invt) {
  int wid = threadIdx.x >> 6;
  int lane = threadIdx.x & 63;
  int d = blockIdx.x * 4 + wid;
  if (d >= NN) return;
  int sw = lane >> 3, hw = lane & 7;
  float adw = ad_[d * 8 + hw];
  float ws = 0.f;
  int p0 = rowp[d], p1 = rowp[d + 1];
  for (int p = p0; p < p1; p += 8) {
    int pe = p + sw;
    bool v = pe < p1;
    int pc = v ? pe : p1 - 1;
    int sW = csr[pc];
    float t = as_[sW * 8 + hw] + adw;
    t = (t > 0.f) ? t : NEG * t;
    float w = v ? __expf(t) : 0.f;
    ws += w;
    if (v) wt[(size_t)hw * ET + pe] = __float2half(w);
  }
  ws += __shfl_xor(ws, 8);
  ws += __shfl_xor(ws, 16);
  ws += __shfl_xor(ws, 32);
  if (sw == 0) invt[d * 8 + hw] = 1.f / (ws + EPSV);
}

// ---------------- pass A: per-edge weights, layer 2 (1 head) --------------
__global__ __launch_bounds__(256) void k_wgt1(const int* __restrict__ rowp,
    const int* __restrict__ csr, const float* __restrict__ as_,
    const float* __restrict__ ad_, __half* __restrict__ wt,
    float* __restrict__ inv2) {
  int wid = threadIdx.x >> 6;
  int lane = threadIdx.x & 63;
  int d = blockIdx.x * 4 + wid;
  if (d >= NN) return;
  float adv = ad_[d];
  float ws = 0.f;
  int p0 = rowp[d], p1 = rowp[d + 1];
  for (int p = p0 + lane; p < p1; p += 64) {
    int s = csr[p];
    float t = as_[s] + adv;
    t = (t > 0.f) ? t : NEG * t;
    float w = __expf(t);
    ws += w;
    wt[p] = __float2half(w);
  }
  ws += __shfl_xor(ws, 1);  ws += __shfl_xor(ws, 2);
  ws += __shfl_xor(ws, 4);  ws += __shfl_xor(ws, 8);
  ws += __shfl_xor(ws, 16); ws += __shfl_xor(ws, 32);
  if (lane == 0) inv2[d] = 1.f / (ws + EPSV);
}

// ---------------- pass B layer 1: full-row gather, precomputed weights -----
// wave/dest, 4 dims/lane (8B). 8-edge aligned macro-iters: 1x16B weight
// broadcast per head-group + 8 independent 512B row gathers. No reduction.
__global__ __launch_bounds__(256) void k_agg1(const int* __restrict__ rowp,
    const int* __restrict__ csr, const __half* __restrict__ wt /*[8][ET]*/,
    const float* __restrict__ inv /*[N][8]*/, const __half* __restrict__ feat,
    const float* __restrict__ bias, __half* __restrict__ outh) {
  int wid = threadIdx.x >> 6;
  int lane = threadIdx.x & 63;
  int d = blockIdx.x * 4 + wid;
  if (d >= NN) return;
  int h = lane >> 3;                      // head of this lane's 4 dims
  int p0 = rowp[d], p1 = rowp[d + 1];
  const __half* wrow = wt + (size_t)h * ET;
  const __half* fcol = feat + lane * 4;
  float a0 = 0.f, a1 = 0.f, a2 = 0.f, a3 = 0.f;
  for (int pb = p0 & ~7; pb < p1; pb += 8) {
    int4 c0 = *(const int4*)(csr + pb);
    int4 c1 = *(const int4*)(csr + pb + 4);
    half8_t wv = *(const half8_t*)(wrow + pb);   // 16B, aligned (ET%8==0)
    int se[8] = {c0.x, c0.y, c0.z, c0.w, c1.x, c1.y, c1.z, c1.w};
    half4_t f[8];
#pragma unroll
    for (int j = 0; j < 8; ++j)
      f[j] = *(const half4_t*)(fcol + (size_t)se[j] * 256);
#pragma unroll
    for (int j = 0; j < 8; ++j) {
      int pe = pb + j;
      float w = (pe >= p0 && pe < p1) ? (float)wv[j] : 0.f;
      a0 = fmaf(w, (float)f[j][0], a0);
      a1 = fmaf(w, (float)f[j][1], a1);
      a2 = fmaf(w, (float)f[j][2], a2);
      a3 = fmaf(w, (float)f[j][3], a3);
    }
  }
  float iv = inv[d * 8 + h];
  int c0i = lane * 4;
  float o0 = fmaxf(fmaf(a0, iv, bias[c0i + 0]), 0.f);
  float o1 = fmaxf(fmaf(a1, iv, bias[c0i + 1]), 0.f);
  float o2 = fmaxf(fmaf(a2, iv, bias[c0i + 2]), 0.f);
  float o3 = fmaxf(fmaf(a3, iv, bias[c0i + 3]), 0.f);
  __half2 pk[2];
  pk[0] = __floats2half2_rn(o0, o1);
  pk[1] = __floats2half2_rn(o2, o3);
  *(float2*)(outh + (size_t)d * 256 + c0i) = *(float2*)pk;
}

// ---------------- pass B layer 2: 2 edge-slots x 32 lanes x half2 ---------
__global__ __launch_bounds__(256) void k_agg2(const int* __restrict__ rowp,
    const int* __restrict__ csr, const __half* __restrict__ wt /*[ET]*/,
    const float* __restrict__ inv2, const __half* __restrict__ feat /*[N][64]*/,
    const float* __restrict__ bias, float* __restrict__ out) {
  int wid = threadIdx.x >> 6;
  int lane = threadIdx.x & 63;
  int d = blockIdx.x * 4 + wid;
  if (d >= NN) return;
  int b = lane >> 5;                      // edge half 0/1
  int q = lane & 31;                      // dim pair
  int p0 = rowp[d], p1 = rowp[d + 1];
  const __half* fcol = feat + q * 2;
  float a0 = 0.f, a1 = 0.f;
  for (int pb = p0 & ~7; pb < p1; pb += 8) {
    int4 c = *(const int4*)(csr + pb + b * 4);
    half4_t wv = *(const half4_t*)(wt + pb + b * 4);   // 8B aligned
    int se[4] = {c.x, c.y, c.z, c.w};
    half2_t f[4];
#pragma unroll
    for (int j = 0; j < 4; ++j)
      f[j] = *(const half2_t*)(fcol + (size_t)se[j] * 64);
#pragma unroll
    for (int j = 0; j < 4; ++j) {
      int pe = pb + b * 4 + j;
      float w = (pe >= p0 && pe < p1) ? (float)wv[j] : 0.f;
      a0 = fmaf(w, (float)f[j][0], a0);
      a1 = fmaf(w, (float)f[j][1], a1);
    }
  }
  a0 += __shfl_xor(a0, 32);
  a1 += __shfl_xor(a1, 32);
  if (b == 0) {
    float iv = inv2[d];
    float2 o;
    o.x = fmaf(a0, iv, bias[q * 2 + 0]);
    o.y = fmaf(a1, iv, bias[q * 2 + 1]);
    *(float2*)(out + (size_t)d * 64 + q * 2) = o;
  }
}

extern "C" void kernel_launch(void* const* d_in, const int* in_sizes, int n_in,
                              void* d_out, int out_size, void* d_ws, size_t ws_size,
                              hipStream_t stream) {
  const float* x    = (const float*)d_in[0];
  const int*   ei   = (const int*)d_in[1];
  const float* W1   = (const float*)d_in[2];
  const float* as1w = (const float*)d_in[3];
  const float* ad1w = (const float*)d_in[4];
  const float* b1   = (const float*)d_in[5];
  const float* W2   = (const float*)d_in[6];
  const float* as2w = (const float*)d_in[7];
  const float* ad2w = (const float*)d_in[8];
  const float* b2   = (const float*)d_in[9];
  float* out = (float*)d_out;

  char* W = (char*)d_ws;
  __half* feat1 = (__half*)W; W += (size_t)NN * 256 * 2;   // GEMM1 out [N][256]
  __half* h2h   = (__half*)W; W += (size_t)NN * 256 * 2;   // agg1 out / GEMM2 A
  __half* feat2 = (__half*)W; W += (size_t)NN * 64 * 2;    // GEMM2 out [N][64]
  __half* W1h   = (__half*)W; W += 256 * 128 * 2;
  __half* W2h   = (__half*)W; W += 64 * 256 * 2;
  __half* w1t   = (__half*)W; W += (size_t)8 * ET * 2;     // [8][ET]
  __half* w2t   = (__half*)W; W += (size_t)ET * 2;         // [ET]
  float* as1   = (float*)W; W += (size_t)NN * 8 * 4;       // [N][8]
  float* ad1   = (float*)W; W += (size_t)NN * 8 * 4;
  float* as2   = (float*)W; W += (size_t)NN * 4;
  float* ad2   = (float*)W; W += (size_t)NN * 4;
  float* inv1  = (float*)W; W += (size_t)NN * 8 * 4;       // [N][8]
  float* inv2  = (float*)W; W += (size_t)NN * 4;
  int* deg    = (int*)W;  W += (size_t)NN * 4;
  int* rowp   = (int*)W;  W += (size_t)(NN + 1) * 4;
  int* cursor = (int*)W;  W += (size_t)NN * 4;
  int* blks   = (int*)W;  W += 256 * 4;
  int* csr    = (int*)W;  W += (size_t)ET * 4;

  hipMemsetAsync(deg, 0, NN * sizeof(int), stream);
  int nbE = (ET + 255) / 256;
  int nbN = (NN + 255) / 256;               // 196
  k_hist<<<nbE, 256, 0, stream>>>(ei, deg);
  k_scan1<<<nbN, 256, 0, stream>>>(deg, rowp, blks);
  k_scan2<<<1, 256, 0, stream>>>(blks, nbN);
  k_scan3<<<nbN, 256, 0, stream>>>(deg, blks, rowp, cursor);
  k_scatter<<<nbE, 256, 0, stream>>>(ei, cursor, csr);

  k_cvtW<<<(W1N4 + W2N4 + 255) / 256, 256, 0, stream>>>(W1, W2, W1h, W2h);

  int mg = (NN + 63) / 64;                  // 782
  int dg = (NN + 3) / 4;                    // 12500

  // layer 1
  k_gemm_mf<128, 128, 256, float><<<dim3(mg, 2), 256, 0, stream>>>(x, W1h, feat1, NN);
  k_att2<H1, D1><<<(NN + 7) / 8, 256, 0, stream>>>(feat1, as1w, ad1w, as1, ad1);
  k_wgt8<<<dg, 256, 0, stream>>>(rowp, csr, as1, ad1, w1t, inv1);
  k_agg1<<<dg, 256, 0, stream>>>(rowp, csr, w1t, inv1, feat1, b1, h2h);

  // layer 2
  k_gemm_mf<64, 256, 64, __half><<<dim3(mg, 1), 256, 0, stream>>>(h2h, W2h, feat2, NN);
  k_att2<1, F2><<<(NN + 31) / 32, 256, 0, stream>>>(feat2, as2w, ad2w, as2, ad2);
  k_wgt1<<<dg, 256, 0, stream>>>(rowp, csr, as2, ad2, w2t, inv2);
  k_agg2<<<dg, 256, 0, stream>>>(rowp, csr, w2t, inv2, feat2, b2, out);
}

// Round 8
// 238.672 us; speedup vs baseline: 1.4241x; 1.1403x over previous
//
#include <hip/hip_runtime.h>
#include <hip/hip_fp16.h>

#define NN 50000
#define EE 800000
#define ET (EE + NN)      // edges + self loops = 850000
#define IND 128
#define F1 256            // HEADS*HID
#define H1 8
#define D1 32
#define F2 64
#define NEG 0.2f
#define EPSV 1e-16f

typedef _Float16 half8_t __attribute__((ext_vector_type(8)));
typedef float floatx4 __attribute__((ext_vector_type(4)));

// ---------------- CSR build ----------------
__global__ void k_hist(const int* __restrict__ ei, int* __restrict__ deg) {
  int e = blockIdx.x * blockDim.x + threadIdx.x;
  if (e >= ET) return;
  int d = (e < EE) ? ei[EE + e] : (e - EE);
  atomicAdd(&deg[d], 1);
}

__global__ void k_scan1(const int* __restrict__ deg, int* __restrict__ incl,
                        int* __restrict__ blks) {
  __shared__ int sm[256];
  int t = threadIdx.x;
  int i = blockIdx.x * 256 + t;
  int v = (i < NN) ? deg[i] : 0;
  sm[t] = v;
  __syncthreads();
  for (int off = 1; off < 256; off <<= 1) {
    int add = (t >= off) ? sm[t - off] : 0;
    __syncthreads();
    sm[t] += add;
    __syncthreads();
  }
  if (i < NN) incl[i] = sm[t];
  if (t == 255) blks[blockIdx.x] = sm[t];
}

__global__ void k_scan2(int* __restrict__ blks, int nb) {
  __shared__ int sm[256];
  int t = threadIdx.x;
  sm[t] = (t < nb) ? blks[t] : 0;
  __syncthreads();
  for (int off = 1; off < 256; off <<= 1) {
    int add = (t >= off) ? sm[t - off] : 0;
    __syncthreads();
    sm[t] += add;
    __syncthreads();
  }
  if (t < nb) blks[t] = sm[t];
}

__global__ void k_scan3(const int* __restrict__ deg, const int* __restrict__ blks,
                        int* __restrict__ rowp, int* __restrict__ cursor) {
  int b = blockIdx.x;
  int i = b * 256 + threadIdx.x;
  if (i == 0) rowp[NN] = ET;
  if (i >= NN) return;
  int base = (b > 0) ? blks[b - 1] : 0;
  int excl = rowp[i] - deg[i] + base;
  rowp[i] = excl;
  cursor[i] = excl;
}

__global__ void k_scatter(const int* __restrict__ ei, int* __restrict__ cursor,
                          int* __restrict__ csr) {
  int e = blockIdx.x * blockDim.x + threadIdx.x;
  if (e >= ET) return;
  int s, d;
  if (e < EE) { s = ei[e]; d = ei[EE + e]; }
  else        { s = e - EE; d = s; }
  int pos = atomicAdd(&cursor[d], 1);
  csr[pos] = s;
}

// ---------------- fused fp32 -> fp16 convert: x | W1 | W2 ----------------
#define XN4 (NN * 128 / 4)
#define W1N4 (256 * 128 / 4)
#define W2N4 (64 * 256 / 4)
__global__ void k_cvt3(const float* __restrict__ x, const float* __restrict__ w1,
                       const float* __restrict__ w2, __half* __restrict__ xh,
                       __half* __restrict__ w1h, __half* __restrict__ w2h) {
  int i = blockIdx.x * blockDim.x + threadIdx.x;
  const float* in;
  __half* o;
  if (i < XN4) { in = x; o = xh; }
  else if (i < XN4 + W1N4) { in = w1; o = w1h; i -= XN4; }
  else if (i < XN4 + W1N4 + W2N4) { in = w2; o = w2h; i -= XN4 + W1N4; }
  else return;
  float4 v = *(const float4*)(in + (size_t)i * 4);
  __half2 p0 = __floats2half2_rn(v.x, v.y);
  __half2 p1 = __floats2half2_rn(v.z, v.w);
  float2 st;
  *(__half2*)&st.x = p0;
  *(__half2*)&st.y = p1;
  *(float2*)(o + (size_t)i * 4) = st;
}

// ---------------- MFMA GEMM: Ch[M,NCF] = A[M,K] * B[NC,K]^T ----------------
// 128 rows/block (2 row-tiles per wave -> each LDS B-frag read feeds 2 MFMAs).
template<int NCT, int K, int NCF>
__global__ __launch_bounds__(256) void k_gemm_mf(const __half* __restrict__ A,
    const __half* __restrict__ Bh, __half* __restrict__ Ch, int M) {
  __shared__ __half Bs[NCT][K + 8];
  int tid = threadIdx.x;
  const float4* src = (const float4*)(Bh + (size_t)blockIdx.y * NCT * K);
  for (int i = tid; i < NCT * K / 8; i += 256) {
    int row = i / (K / 8), kc = i % (K / 8);
    *(float4*)&Bs[row][kc * 8] = src[i];
  }
  __syncthreads();
  int wv = tid >> 6, lane = tid & 63;
  int m0 = blockIdx.x * 128 + wv * 16;
  int ar = lane & 15, ag = lane >> 4;
  int r0 = m0 + ar;       if (r0 >= M) r0 = M - 1;
  int r1 = m0 + 64 + ar;  if (r1 >= M) r1 = M - 1;
  const __half* A0 = A + (size_t)r0 * K + ag * 8;
  const __half* A1 = A + (size_t)r1 * K + ag * 8;
  floatx4 acc[2][NCT / 16];
#pragma unroll
  for (int rt = 0; rt < 2; ++rt)
#pragma unroll
    for (int t = 0; t < NCT / 16; ++t) acc[rt][t] = (floatx4){0.f, 0.f, 0.f, 0.f};
#pragma unroll
  for (int k0 = 0; k0 < K; k0 += 32) {
    half8_t af0 = *(const half8_t*)(A0 + k0);
    half8_t af1 = *(const half8_t*)(A1 + k0);
#pragma unroll
    for (int t = 0; t < NCT / 16; ++t) {
      half8_t bf = *(const half8_t*)&Bs[t * 16 + ar][k0 + ag * 8];
      acc[0][t] = __builtin_amdgcn_mfma_f32_16x16x32_f16(af0, bf, acc[0][t], 0, 0, 0);
      acc[1][t] = __builtin_amdgcn_mfma_f32_16x16x32_f16(af1, bf, acc[1][t], 0, 0, 0);
    }
  }
#pragma unroll
  for (int rt = 0; rt < 2; ++rt)
#pragma unroll
    for (int t = 0; t < NCT / 16; ++t) {
      int col = blockIdx.y * NCT + t * 16 + ar;
#pragma unroll
      for (int r = 0; r < 4; ++r) {
        int m = m0 + rt * 64 + ag * 4 + r;
        if (m < M) Ch[(size_t)m * NCF + col] = __float2half(acc[rt][t][r]);
      }
    }
}

// ---------------- per-node attention logits, coalesced ----------------
// Wave covers 64/(F/8) nodes; each lane one 16B chunk (8 dims).
template<int H, int D>
__global__ void k_att2(const __half* __restrict__ h, const float* __restrict__ atts,
                       const float* __restrict__ attd, float* __restrict__ as_,
                       float* __restrict__ ad_) {
  const int F = H * D;
  const int CPR = F / 8;          // chunks per row
  const int NPW = 64 / CPR;       // nodes per wave
  const int CPH = D / 8;          // chunks per head
  int lane = threadIdx.x & 63;
  int wv = threadIdx.x >> 6;
  int n = blockIdx.x * (4 * NPW) + wv * NPW + lane / CPR;
  if (n >= NN) return;
  int c = lane % CPR;
  int head = c / CPH;
  int within = c % CPH;
  half8_t f = *(const half8_t*)(h + (size_t)n * F + c * 8);
  float s_ = 0.f, d_ = 0.f;
#pragma unroll
  for (int j = 0; j < 8; ++j) {
    float fv = (float)f[j];
    s_ += fv * atts[head * D + within * 8 + j];
    d_ += fv * attd[head * D + within * 8 + j];
  }
#pragma unroll
  for (int m = 1; m < CPH; m <<= 1) {
    s_ += __shfl_xor(s_, m);
    d_ += __shfl_xor(d_, m);
  }
  if (within == 0) {
    as_[n * H + head] = s_;
    ad_[n * H + head] = d_;
  }
}

// ---------------- layer-1 aggregation ----------------
// Wave per dest. Macro-iter = 8 edges. Weight phase: lane = (slot 0..7, head
// 0..7) computes ONE (edge,head) weight. Dim phase: 2 edges x 32 lanes x 16B,
// weights/srcs redistributed via ds_bpermute. fp32 accum. Softmax folded
// into the final divide.
__global__ __launch_bounds__(256) void k_agg1(const int* __restrict__ rowp,
    const int* __restrict__ csr, const __half* __restrict__ feat,
    const float* __restrict__ as_, const float* __restrict__ ad_,
    const float* __restrict__ bias, __half* __restrict__ outh) {
  int wid = threadIdx.x >> 6;
  int lane = threadIdx.x & 63;
  int d = blockIdx.x * 4 + wid;
  if (d >= NN) return;
  const int b = lane >> 5;        // edge parity (dim phase)
  const int q = lane & 31;        // 16B chunk within row
  const int h = q >> 2;           // head of this chunk
  const int sw = lane >> 3;       // weight-phase slot
  const int hw = lane & 7;        // weight-phase head
  const char* fb = (const char*)feat;
  float adw = ad_[d * 8 + hw];
  float acc[8] = {};
  float wsacc = 0.f;
  int p0 = rowp[d], p1 = rowp[d + 1];
  int nfull = (p1 - p0) >> 3;
  int p = p0;
  for (int it = 0; it < nfull; ++it, p += 8) {
    int sW = csr[p + sw];
    float t = as_[sW * 8 + hw] + adw;
    t = (t > 0.f) ? t : NEG * t;
    float w = __expf(t);
    wsacc += w;
    int wbits = __float_as_int(w);
#pragma unroll
    for (int i = 0; i < 4; ++i) {
      int slot = 2 * i + b;
      int se = __builtin_amdgcn_ds_bpermute(slot * 32, sW);
      float wv = __int_as_float(
          __builtin_amdgcn_ds_bpermute((slot * 8 + h) * 4, wbits));
      half8_t f = *(const half8_t*)(fb + ((se << 9) | (q << 4)));
#pragma unroll
      for (int j = 0; j < 8; ++j) acc[j] = fmaf(wv, (float)f[j], acc[j]);
    }
  }
  if (p < p1) {                   // masked tail macro-iter
    int pw = p + sw;
    bool v = pw < p1;
    int sW = csr[v ? pw : (p1 - 1)];
    float t = as_[sW * 8 + hw] + adw;
    t = (t > 0.f) ? t : NEG * t;
    float w = v ? __expf(t) : 0.f;
    wsacc += w;
    int wbits = __float_as_int(w);
#pragma unroll
    for (int i = 0; i < 4; ++i) {
      int slot = 2 * i + b;
      int se = __builtin_amdgcn_ds_bpermute(slot * 32, sW);
      float wv = __int_as_float(
          __builtin_amdgcn_ds_bpermute((slot * 8 + h) * 4, wbits));
      half8_t f = *(const half8_t*)(fb + ((se << 9) | (q << 4)));
#pragma unroll
      for (int j = 0; j < 8; ++j) acc[j] = fmaf(wv, (float)f[j], acc[j]);
    }
  }
  // ws: reduce over slots (lane bits 3,4,5) -> lane L holds total for head L&7
  wsacc += __shfl_xor(wsacc, 8);
  wsacc += __shfl_xor(wsacc, 16);
  wsacc += __shfl_xor(wsacc, 32);
  float wst = __int_as_float(
      __builtin_amdgcn_ds_bpermute(h * 4, __float_as_int(wsacc)));
  // acc: combine the two edge-parity halves
#pragma unroll
  for (int j = 0; j < 8; ++j) acc[j] += __shfl_xor(acc[j], 32);
  if (b == 0) {
    float inv = 1.f / (wst + EPSV);
    __half2 packs[4];
#pragma unroll
    for (int j = 0; j < 8; j += 2) {
      float o0 = fmaxf(fmaf(acc[j], inv, 0.f) + bias[q * 8 + j], 0.f);
      float o1 = fmaxf(fmaf(acc[j + 1], inv, 0.f) + bias[q * 8 + j + 1], 0.f);
      packs[j >> 1] = __floats2half2_rn(o0, o1);
    }
    *(float4*)(outh + (size_t)d * 256 + q * 8) = *(float4*)packs;
  }
}

// ---------------- layer-2 aggregation: 8 edges/iter x 8 lanes x 16B --------
__global__ __launch_bounds__(256) void k_agg2(const int* __restrict__ rowp,
    const int* __restrict__ csr, const __half* __restrict__ feat /*[N][64]*/,
    const float* __restrict__ as_, const float* __restrict__ ad_,
    const float* __restrict__ bias, float* __restrict__ out) {
  int wid = threadIdx.x >> 6;
  int lane = threadIdx.x & 63;
  int d = blockIdx.x * 4 + wid;
  if (d >= NN) return;
  const int b = lane >> 3;        // edge slot 0..7
  const int q = lane & 7;         // 16B chunk
  const char* fb = (const char*)feat;
  float adv = ad_[d];
  float acc[8] = {};
  float ws = 0.f;
  int p0 = rowp[d], p1 = rowp[d + 1];
  int nfull = (p1 - p0) >> 3;
  int p = p0;
  for (int it = 0; it < nfull; ++it, p += 8) {
    int se = csr[p + b];
    float t = as_[se] + adv;
    t = (t > 0.f) ? t : NEG * t;
    float w = __expf(t);
    ws += w;
    half8_t f = *(const half8_t*)(fb + ((se << 7) | (q << 4)));
#pragma unroll
    for (int j = 0; j < 8; ++j) acc[j] = fmaf(w, (float)f[j], acc[j]);
  }
  if (p < p1) {
    int pe = p + b;
    bool v = pe < p1;
    int se = csr[v ? pe : (p1 - 1)];
    float t = as_[se] + adv;
    t = (t > 0.f) ? t : NEG * t;
    float w = v ? __expf(t) : 0.f;
    ws += w;
    half8_t f = *(const half8_t*)(fb + ((se << 7) | (q << 4)));
#pragma unroll
    for (int j = 0; j < 8; ++j) acc[j] = fmaf(w, (float)f[j], acc[j]);
  }
  ws += __shfl_xor(ws, 8);
  ws += __shfl_xor(ws, 16);
  ws += __shfl_xor(ws, 32);
#pragma unroll
  for (int j = 0; j < 8; ++j) {
    acc[j] += __shfl_xor(acc[j], 8);
    acc[j] += __shfl_xor(acc[j], 16);
    acc[j] += __shfl_xor(acc[j], 32);
  }
  if (b == 0) {
    float inv = 1.f / (ws + EPSV);
    float o[8];
#pragma unroll
    for (int j = 0; j < 8; ++j) o[j] = acc[j] * inv + bias[q * 8 + j];
    *(float4*)(out + (size_t)d * 64 + q * 8) = *(float4*)&o[0];
    *(float4*)(out + (size_t)d * 64 + q * 8 + 4) = *(float4*)&o[4];
  }
}

extern "C" void kernel_launch(void* const* d_in, const int* in_sizes, int n_in,
                              void* d_out, int out_size, void* d_ws, size_t ws_size,
                              hipStream_t stream) {
  const float* x    = (const float*)d_in[0];
  const int*   ei   = (const int*)d_in[1];
  const float* W1   = (const float*)d_in[2];
  const float* as1w = (const float*)d_in[3];
  const float* ad1w = (const float*)d_in[4];
  const float* b1   = (const float*)d_in[5];
  const float* W2   = (const float*)d_in[6];
  const float* as2w = (const float*)d_in[7];
  const float* ad2w = (const float*)d_in[8];
  const float* b2   = (const float*)d_in[9];
  float* out = (float*)d_out;

  char* W = (char*)d_ws;
  __half* h1h = (__half*)W; W += (size_t)NN * 256 * 2;   // GEMM1 out / att1+agg1 in
  __half* h2h = (__half*)W; W += (size_t)NN * 256 * 2;   // agg1 out / GEMM2 A
  __half* hmh = (__half*)W; W += (size_t)NN * 64 * 2;    // GEMM2 out / att2+agg2 in
  __half* xh  = (__half*)W; W += (size_t)NN * 128 * 2;
  __half* W1h = (__half*)W; W += 256 * 128 * 2;
  __half* W2h = (__half*)W; W += 64 * 256 * 2;
  float* as1 = (float*)W; W += (size_t)NN * 8 * 4;       // node-major [N][8]
  float* ad1 = (float*)W; W += (size_t)NN * 8 * 4;
  float* as2 = (float*)W; W += (size_t)NN * 4;
  float* ad2 = (float*)W; W += (size_t)NN * 4;
  int* deg    = (int*)W;  W += (size_t)NN * 4;
  int* rowp   = (int*)W;  W += (size_t)(NN + 1) * 4;
  int* cursor = (int*)W;  W += (size_t)NN * 4;
  int* blks   = (int*)W;  W += 256 * 4;
  int* csr    = (int*)W;  W += (size_t)ET * 4;

  hipMemsetAsync(deg, 0, NN * sizeof(int), stream);
  int nbE = (ET + 255) / 256;
  int nbN = (NN + 255) / 256;               // 196
  k_hist<<<nbE, 256, 0, stream>>>(ei, deg);
  k_scan1<<<nbN, 256, 0, stream>>>(deg, rowp, blks);
  k_scan2<<<1, 256, 0, stream>>>(blks, nbN);
  k_scan3<<<nbN, 256, 0, stream>>>(deg, blks, rowp, cursor);
  k_scatter<<<nbE, 256, 0, stream>>>(ei, cursor, csr);

  int cvtn = XN4 + W1N4 + W2N4;
  k_cvt3<<<(cvtn + 255) / 256, 256, 0, stream>>>(x, W1, W2, xh, W1h, W2h);

  int mg2 = (NN + 127) / 128;               // 391

  // layer 1
  k_gemm_mf<128, 128, 256><<<dim3(mg2, 2), 256, 0, stream>>>(xh, W1h, h1h, NN);
  k_att2<H1, D1><<<(NN + 7) / 8, 256, 0, stream>>>(h1h, as1w, ad1w, as1, ad1);
  k_agg1<<<(NN + 3) / 4, 256, 0, stream>>>(rowp, csr, h1h, as1, ad1, b1, h2h);

  // layer 2
  k_gemm_mf<64, 256, 64><<<dim3(mg2, 1), 256, 0, stream>>>(h2h, W2h, hmh, NN);
  k_att2<1, F2><<<(NN + 31) / 32, 256, 0, stream>>>(hmh, as2w, ad2w, as2, ad2);
  k_agg2<<<(NN + 3) / 4, 256, 0, stream>>>(rowp, csr, hmh, as2, ad2, b2, out);
}

// Round 9
// 227.549 us; speedup vs baseline: 1.4937x; 1.0489x over previous
//
#include <hip/hip_runtime.h>
#include <hip/hip_fp16.h>

#define NN 50000
#define EE 800000
#define ET (EE + NN)      // edges + self loops = 850000
#define IND 128
#define F1 256            // HEADS*HID
#define H1 8
#define D1 32
#define F2 64
#define NEG 0.2f
#define EPSV 1e-16f

#define MG2 391           // (NN+127)/128
#define NBE 3321          // (ET+255)/256
#define NBN 196           // (NN+255)/256

typedef _Float16 half8_t __attribute__((ext_vector_type(8)));
typedef float floatx4 __attribute__((ext_vector_type(4)));

// ---------------- K1: histogram + W1/W2 fp16 conversion ----------------
#define W1N4 (256 * 128 / 4)   // 8192 float4s
#define W2N4 (64 * 256 / 4)    // 4096 float4s
#define NCVT ((W1N4 + W2N4 + 255) / 256)   // 48 blocks
__global__ void k_histcvt(const int* __restrict__ ei, int* __restrict__ deg,
                          const float* __restrict__ w1, const float* __restrict__ w2,
                          __half* __restrict__ w1h, __half* __restrict__ w2h) {
  if (blockIdx.x < NBE) {
    int e = blockIdx.x * 256 + threadIdx.x;
    if (e >= ET) return;
    int d = (e < EE) ? ei[EE + e] : (e - EE);
    atomicAdd(&deg[d], 1);
    return;
  }
  int i = (blockIdx.x - NBE) * 256 + threadIdx.x;
  const float* in;
  __half* o;
  if (i < W1N4) { in = w1; o = w1h; }
  else if (i < W1N4 + W2N4) { in = w2; o = w2h; i -= W1N4; }
  else return;
  float4 v = *(const float4*)(in + (size_t)i * 4);
  __half2 p0 = __floats2half2_rn(v.x, v.y);
  __half2 p1 = __floats2half2_rn(v.z, v.w);
  float2 st;
  *(__half2*)&st.x = p0;
  *(__half2*)&st.y = p1;
  *(float2*)(o + (size_t)i * 4) = st;
}

// ---------------- K2: per-block inclusive scan of deg ----------------
__global__ void k_scan1(const int* __restrict__ deg, int* __restrict__ incl,
                        int* __restrict__ blks) {
  __shared__ int sm[256];
  int t = threadIdx.x;
  int i = blockIdx.x * 256 + t;
  int v = (i < NN) ? deg[i] : 0;
  sm[t] = v;
  __syncthreads();
  for (int off = 1; off < 256; off <<= 1) {
    int add = (t >= off) ? sm[t - off] : 0;
    __syncthreads();
    sm[t] += add;
    __syncthreads();
  }
  if (i < NN) incl[i] = sm[t];
  if (t == 255) blks[blockIdx.x] = sm[t];
}

// ---------------- K3: fused block-sum scan + finalize (scan2+scan3) -------
// Every block redundantly scans blks[0..NBN) in LDS, then finalizes its range.
__global__ void k_scan23(const int* __restrict__ deg, const int* __restrict__ blks,
                         int* __restrict__ rowp, int* __restrict__ cursor) {
  __shared__ int sm[256];
  int t = threadIdx.x;
  sm[t] = (t < NBN) ? blks[t] : 0;
  __syncthreads();
  for (int off = 1; off < 256; off <<= 1) {
    int add = (t >= off) ? sm[t - off] : 0;
    __syncthreads();
    sm[t] += add;
    __syncthreads();
  }
  int b = blockIdx.x;
  int i = b * 256 + t;
  if (i == 0) rowp[NN] = ET;
  if (i >= NN) return;
  int base = (b > 0) ? sm[b - 1] : 0;
  int excl = rowp[i] - deg[i] + base;   // rowp currently holds block-local incl
  rowp[i] = excl;
  cursor[i] = excl;
}

// ---------------- K4: GEMM1 (fp32 A, fp16 out) || CSR scatter ----------------
// blocks [0, 2*MG2): 128x128 GEMM tiles (bx = b%MG2 rows, by = b/MG2 cols).
// blocks [2*MG2, ...): edge scatter (overlaps with MFMA work).
__global__ __launch_bounds__(256) void k_g1sc(const float* __restrict__ A,
    const __half* __restrict__ Bh, __half* __restrict__ Ch,
    const int* __restrict__ ei, int* __restrict__ cursor, int* __restrict__ csr) {
  __shared__ __half Bs[128][128 + 8];
  if (blockIdx.x >= 2 * MG2) {
    int e = (blockIdx.x - 2 * MG2) * 256 + threadIdx.x;
    if (e >= ET) return;
    int s, d;
    if (e < EE) { s = ei[e]; d = ei[EE + e]; }
    else        { s = e - EE; d = s; }
    int pos = atomicAdd(&cursor[d], 1);
    csr[pos] = s;
    return;
  }
  int bx = blockIdx.x % MG2, by = blockIdx.x / MG2;
  int tid = threadIdx.x;
  const float4* src = (const float4*)(Bh + (size_t)by * 128 * 128);
  for (int i = tid; i < 128 * 128 / 8; i += 256) {
    int row = i / 16, kc = i % 16;
    *(float4*)&Bs[row][kc * 8] = src[i];
  }
  __syncthreads();
  int wv = tid >> 6, lane = tid & 63;
  int m0 = bx * 128 + wv * 16;
  int ar = lane & 15, ag = lane >> 4;
  int r0 = m0 + ar;       if (r0 >= NN) r0 = NN - 1;
  int r1 = m0 + 64 + ar;  if (r1 >= NN) r1 = NN - 1;
  const float* A0 = A + (size_t)r0 * IND + ag * 8;
  const float* A1 = A + (size_t)r1 * IND + ag * 8;
  floatx4 acc[2][8];
#pragma unroll
  for (int rt = 0; rt < 2; ++rt)
#pragma unroll
    for (int t = 0; t < 8; ++t) acc[rt][t] = (floatx4){0.f, 0.f, 0.f, 0.f};
#pragma unroll
  for (int k0 = 0; k0 < IND; k0 += 32) {
    float4 a00 = *(const float4*)(A0 + k0);
    float4 a01 = *(const float4*)(A0 + k0 + 4);
    float4 a10 = *(const float4*)(A1 + k0);
    float4 a11 = *(const float4*)(A1 + k0 + 4);
    half8_t af0, af1;
    af0[0] = (_Float16)a00.x; af0[1] = (_Float16)a00.y;
    af0[2] = (_Float16)a00.z; af0[3] = (_Float16)a00.w;
    af0[4] = (_Float16)a01.x; af0[5] = (_Float16)a01.y;
    af0[6] = (_Float16)a01.z; af0[7] = (_Float16)a01.w;
    af1[0] = (_Float16)a10.x; af1[1] = (_Float16)a10.y;
    af1[2] = (_Float16)a10.z; af1[3] = (_Float16)a10.w;
    af1[4] = (_Float16)a11.x; af1[5] = (_Float16)a11.y;
    af1[6] = (_Float16)a11.z; af1[7] = (_Float16)a11.w;
#pragma unroll
    for (int t = 0; t < 8; ++t) {
      half8_t bf = *(const half8_t*)&Bs[t * 16 + ar][k0 + ag * 8];
      acc[0][t] = __builtin_amdgcn_mfma_f32_16x16x32_f16(af0, bf, acc[0][t], 0, 0, 0);
      acc[1][t] = __builtin_amdgcn_mfma_f32_16x16x32_f16(af1, bf, acc[1][t], 0, 0, 0);
    }
  }
#pragma unroll
  for (int rt = 0; rt < 2; ++rt)
#pragma unroll
    for (int t = 0; t < 8; ++t) {
      int col = by * 128 + t * 16 + ar;
#pragma unroll
      for (int r = 0; r < 4; ++r) {
        int m = m0 + rt * 64 + ag * 4 + r;
        if (m < NN) Ch[(size_t)m * F1 + col] = __float2half(acc[rt][t][r]);
      }
    }
}

// ---------------- per-node attention logits (layer 1), coalesced ----------
template<int H, int D>
__global__ void k_att2(const __half* __restrict__ h, const float* __restrict__ atts,
                       const float* __restrict__ attd, float* __restrict__ as_,
                       float* __restrict__ ad_) {
  const int F = H * D;
  const int CPR = F / 8;
  const int NPW = 64 / CPR;
  const int CPH = D / 8;
  int lane = threadIdx.x & 63;
  int wv = threadIdx.x >> 6;
  int n = blockIdx.x * (4 * NPW) + wv * NPW + lane / CPR;
  if (n >= NN) return;
  int c = lane % CPR;
  int head = c / CPH;
  int within = c % CPH;
  half8_t f = *(const half8_t*)(h + (size_t)n * F + c * 8);
  float s_ = 0.f, d_ = 0.f;
#pragma unroll
  for (int j = 0; j < 8; ++j) {
    float fv = (float)f[j];
    s_ += fv * atts[head * D + within * 8 + j];
    d_ += fv * attd[head * D + within * 8 + j];
  }
#pragma unroll
  for (int m = 1; m < CPH; m <<= 1) {
    s_ += __shfl_xor(s_, m);
    d_ += __shfl_xor(d_, m);
  }
  if (within == 0) {
    as_[n * H + head] = s_;
    ad_[n * H + head] = d_;
  }
}

// ---------------- layer-1 aggregation (unchanged, at measured floor) ------
__global__ __launch_bounds__(256) void k_agg1(const int* __restrict__ rowp,
    const int* __restrict__ csr, const __half* __restrict__ feat,
    const float* __restrict__ as_, const float* __restrict__ ad_,
    const float* __restrict__ bias, __half* __restrict__ outh) {
  int wid = threadIdx.x >> 6;
  int lane = threadIdx.x & 63;
  int d = blockIdx.x * 4 + wid;
  if (d >= NN) return;
  const int b = lane >> 5;
  const int q = lane & 31;
  const int h = q >> 2;
  const int sw = lane >> 3;
  const int hw = lane & 7;
  const char* fb = (const char*)feat;
  float adw = ad_[d * 8 + hw];
  float acc[8] = {};
  float wsacc = 0.f;
  int p0 = rowp[d], p1 = rowp[d + 1];
  int nfull = (p1 - p0) >> 3;
  int p = p0;
  for (int it = 0; it < nfull; ++it, p += 8) {
    int sW = csr[p + sw];
    float t = as_[sW * 8 + hw] + adw;
    t = (t > 0.f) ? t : NEG * t;
    float w = __expf(t);
    wsacc += w;
    int wbits = __float_as_int(w);
#pragma unroll
    for (int i = 0; i < 4; ++i) {
      int slot = 2 * i + b;
      int se = __builtin_amdgcn_ds_bpermute(slot * 32, sW);
      float wv = __int_as_float(
          __builtin_amdgcn_ds_bpermute((slot * 8 + h) * 4, wbits));
      half8_t f = *(const half8_t*)(fb + ((se << 9) | (q << 4)));
#pragma unroll
      for (int j = 0; j < 8; ++j) acc[j] = fmaf(wv, (float)f[j], acc[j]);
    }
  }
  if (p < p1) {
    int pw = p + sw;
    bool v = pw < p1;
    int sW = csr[v ? pw : (p1 - 1)];
    float t = as_[sW * 8 + hw] + adw;
    t = (t > 0.f) ? t : NEG * t;
    float w = v ? __expf(t) : 0.f;
    wsacc += w;
    int wbits = __float_as_int(w);
#pragma unroll
    for (int i = 0; i < 4; ++i) {
      int slot = 2 * i + b;
      int se = __builtin_amdgcn_ds_bpermute(slot * 32, sW);
      float wv = __int_as_float(
          __builtin_amdgcn_ds_bpermute((slot * 8 + h) * 4, wbits));
      half8_t f = *(const half8_t*)(fb + ((se << 9) | (q << 4)));
#pragma unroll
      for (int j = 0; j < 8; ++j) acc[j] = fmaf(wv, (float)f[j], acc[j]);
    }
  }
  wsacc += __shfl_xor(wsacc, 8);
  wsacc += __shfl_xor(wsacc, 16);
  wsacc += __shfl_xor(wsacc, 32);
  float wst = __int_as_float(
      __builtin_amdgcn_ds_bpermute(h * 4, __float_as_int(wsacc)));
#pragma unroll
  for (int j = 0; j < 8; ++j) acc[j] += __shfl_xor(acc[j], 32);
  if (b == 0) {
    float inv = 1.f / (wst + EPSV);
    __half2 packs[4];
#pragma unroll
    for (int j = 0; j < 8; j += 2) {
      float o0 = fmaxf(fmaf(acc[j], inv, 0.f) + bias[q * 8 + j], 0.f);
      float o1 = fmaxf(fmaf(acc[j + 1], inv, 0.f) + bias[q * 8 + j + 1], 0.f);
      packs[j >> 1] = __floats2half2_rn(o0, o1);
    }
    *(float4*)(outh + (size_t)d * 256 + q * 8) = *(float4*)packs;
  }
}

// ---------------- K7: GEMM2 (fp16) with fused att2 epilogue ----------------
// 128 rows x 64 cols per block; block covers ALL cols -> full att2 dot per
// row computed from fp32 acc: shfl-reduce over the 16 ar lanes.
__global__ __launch_bounds__(256) void k_g2att(const __half* __restrict__ A,
    const __half* __restrict__ Bh, __half* __restrict__ Ch,
    const float* __restrict__ as2w, const float* __restrict__ ad2w,
    float* __restrict__ as2, float* __restrict__ ad2) {
  __shared__ __half Bs[64][256 + 8];
  int tid = threadIdx.x;
  const float4* src = (const float4*)Bh;
  for (int i = tid; i < 64 * 256 / 8; i += 256) {
    int row = i / 32, kc = i % 32;
    *(float4*)&Bs[row][kc * 8] = src[i];
  }
  __syncthreads();
  int wv = tid >> 6, lane = tid & 63;
  int m0 = blockIdx.x * 128 + wv * 16;
  int ar = lane & 15, ag = lane >> 4;
  int r0 = m0 + ar;       if (r0 >= NN) r0 = NN - 1;
  int r1 = m0 + 64 + ar;  if (r1 >= NN) r1 = NN - 1;
  const __half* A0 = A + (size_t)r0 * F1 + ag * 8;
  const __half* A1 = A + (size_t)r1 * F1 + ag * 8;
  floatx4 acc[2][4];
#pragma unroll
  for (int rt = 0; rt < 2; ++rt)
#pragma unroll
    for (int t = 0; t < 4; ++t) acc[rt][t] = (floatx4){0.f, 0.f, 0.f, 0.f};
#pragma unroll
  for (int k0 = 0; k0 < F1; k0 += 32) {
    half8_t af0 = *(const half8_t*)(A0 + k0);
    half8_t af1 = *(const half8_t*)(A1 + k0);
#pragma unroll
    for (int t = 0; t < 4; ++t) {
      half8_t bf = *(const half8_t*)&Bs[t * 16 + ar][k0 + ag * 8];
      acc[0][t] = __builtin_amdgcn_mfma_f32_16x16x32_f16(af0, bf, acc[0][t], 0, 0, 0);
      acc[1][t] = __builtin_amdgcn_mfma_f32_16x16x32_f16(af1, bf, acc[1][t], 0, 0, 0);
    }
  }
  float sp[2][4] = {}, dp[2][4] = {};
#pragma unroll
  for (int t = 0; t < 4; ++t) {
    int col = t * 16 + ar;
    float ws = as2w[col], wd = ad2w[col];
#pragma unroll
    for (int rt = 0; rt < 2; ++rt)
#pragma unroll
      for (int r = 0; r < 4; ++r) {
        int m = m0 + rt * 64 + ag * 4 + r;
        if (m < NN) Ch[(size_t)m * F2 + col] = __float2half(acc[rt][t][r]);
        sp[rt][r] = fmaf(acc[rt][t][r], ws, sp[rt][r]);
        dp[rt][r] = fmaf(acc[rt][t][r], wd, dp[rt][r]);
      }
  }
#pragma unroll
  for (int msk = 1; msk < 16; msk <<= 1)
#pragma unroll
    for (int rt = 0; rt < 2; ++rt)
#pragma unroll
      for (int r = 0; r < 4; ++r) {
        sp[rt][r] += __shfl_xor(sp[rt][r], msk);
        dp[rt][r] += __shfl_xor(dp[rt][r], msk);
      }
  if (ar == 0) {
#pragma unroll
    for (int rt = 0; rt < 2; ++rt)
#pragma unroll
      for (int r = 0; r < 4; ++r) {
        int m = m0 + rt * 64 + ag * 4 + r;
        if (m < NN) { as2[m] = sp[rt][r]; ad2[m] = dp[rt][r]; }
      }
  }
}

// ---------------- layer-2 aggregation (unchanged, at measured floor) ------
__global__ __launch_bounds__(256) void k_agg2(const int* __restrict__ rowp,
    const int* __restrict__ csr, const __half* __restrict__ feat /*[N][64]*/,
    const float* __restrict__ as_, const float* __restrict__ ad_,
    const float* __restrict__ bias, float* __restrict__ out) {
  int wid = threadIdx.x >> 6;
  int lane = threadIdx.x & 63;
  int d = blockIdx.x * 4 + wid;
  if (d >= NN) return;
  const int b = lane >> 3;
  const int q = lane & 7;
  const char* fb = (const char*)feat;
  float adv = ad_[d];
  float acc[8] = {};
  float ws = 0.f;
  int p0 = rowp[d], p1 = rowp[d + 1];
  int nfull = (p1 - p0) >> 3;
  int p = p0;
  for (int it = 0; it < nfull; ++it, p += 8) {
    int se = csr[p + b];
    float t = as_[se] + adv;
    t = (t > 0.f) ? t : NEG * t;
    float w = __expf(t);
    ws += w;
    half8_t f = *(const half8_t*)(fb + ((se << 7) | (q << 4)));
#pragma unroll
    for (int j = 0; j < 8; ++j) acc[j] = fmaf(w, (float)f[j], acc[j]);
  }
  if (p < p1) {
    int pe = p + b;
    bool v = pe < p1;
    int se = csr[v ? pe : (p1 - 1)];
    float t = as_[se] + adv;
    t = (t > 0.f) ? t : NEG * t;
    float w = v ? __expf(t) : 0.f;
    ws += w;
    half8_t f = *(const half8_t*)(fb + ((se << 7) | (q << 4)));
#pragma unroll
    for (int j = 0; j < 8; ++j) acc[j] = fmaf(w, (float)f[j], acc[j]);
  }
  ws += __shfl_xor(ws, 8);
  ws += __shfl_xor(ws, 16);
  ws += __shfl_xor(ws, 32);
#pragma unroll
  for (int j = 0; j < 8; ++j) {
    acc[j] += __shfl_xor(acc[j], 8);
    acc[j] += __shfl_xor(acc[j], 16);
    acc[j] += __shfl_xor(acc[j], 32);
  }
  if (b == 0) {
    float inv = 1.f / (ws + EPSV);
    float o[8];
#pragma unroll
    for (int j = 0; j < 8; ++j) o[j] = acc[j] * inv + bias[q * 8 + j];
    *(float4*)(out + (size_t)d * 64 + q * 8) = *(float4*)&o[0];
    *(float4*)(out + (size_t)d * 64 + q * 8 + 4) = *(float4*)&o[4];
  }
}

extern "C" void kernel_launch(void* const* d_in, const int* in_sizes, int n_in,
                              void* d_out, int out_size, void* d_ws, size_t ws_size,
                              hipStream_t stream) {
  const float* x    = (const float*)d_in[0];
  const int*   ei   = (const int*)d_in[1];
  const float* W1   = (const float*)d_in[2];
  const float* as1w = (const float*)d_in[3];
  const float* ad1w = (const float*)d_in[4];
  const float* b1   = (const float*)d_in[5];
  const float* W2   = (const float*)d_in[6];
  const float* as2w = (const float*)d_in[7];
  const float* ad2w = (const float*)d_in[8];
  const float* b2   = (const float*)d_in[9];
  float* out = (float*)d_out;

  char* W = (char*)d_ws;
  __half* h1h = (__half*)W; W += (size_t)NN * 256 * 2;   // GEMM1 out / att1+agg1 in
  __half* h2h = (__half*)W; W += (size_t)NN * 256 * 2;   // agg1 out / GEMM2 A
  __half* hmh = (__half*)W; W += (size_t)NN * 64 * 2;    // GEMM2 out / agg2 in
  __half* W1h = (__half*)W; W += 256 * 128 * 2;
  __half* W2h = (__half*)W; W += 64 * 256 * 2;
  float* as1 = (float*)W; W += (size_t)NN * 8 * 4;       // node-major [N][8]
  float* ad1 = (float*)W; W += (size_t)NN * 8 * 4;
  float* as2 = (float*)W; W += (size_t)NN * 4;
  float* ad2 = (float*)W; W += (size_t)NN * 4;
  int* deg    = (int*)W;  W += (size_t)NN * 4;
  int* rowp   = (int*)W;  W += (size_t)(NN + 1) * 4;
  int* cursor = (int*)W;  W += (size_t)NN * 4;
  int* blks   = (int*)W;  W += 256 * 4;
  int* csr    = (int*)W;  W += (size_t)ET * 4;

  hipMemsetAsync(deg, 0, NN * sizeof(int), stream);

  // K1: hist + W cvt
  k_histcvt<<<NBE + NCVT, 256, 0, stream>>>(ei, deg, W1, W2, W1h, W2h);
  // K2/K3: scan
  k_scan1<<<NBN, 256, 0, stream>>>(deg, rowp, blks);
  k_scan23<<<NBN, 256, 0, stream>>>(deg, blks, rowp, cursor);
  // K4: GEMM1 (fp32 A) || scatter
  k_g1sc<<<2 * MG2 + NBE, 256, 0, stream>>>(x, W1h, h1h, ei, cursor, csr);
  // K5: att1
  k_att2<H1, D1><<<(NN + 7) / 8, 256, 0, stream>>>(h1h, as1w, ad1w, as1, ad1);
  // K6: agg1
  k_agg1<<<(NN + 3) / 4, 256, 0, stream>>>(rowp, csr, h1h, as1, ad1, b1, h2h);
  // K7: GEMM2 + att2
  k_g2att<<<MG2, 256, 0, stream>>>(h2h, W2h, hmh, as2w, ad2w, as2, ad2);
  // K8: agg2
  k_agg2<<<(NN + 3) / 4, 256, 0, stream>>>(rowp, csr, hmh, as2, ad2, b2, out);
}